// Round 22
// baseline (56.686 us; speedup 1.0000x reference)
//
#include <hip/hip_runtime.h>
#include <math.h>

// ConcentrationPredictor: 32 RK4 steps of dc/dt = flux(c), per-cell MLP D_eff.
// R22 = R21 (single rk4 dispatch, grid 256 = 1 block/CU, duplicated-pair
// float4 table -> one ds_read_b128/eval, hoisted gathers, LDS A[s],
// lgkm-only raw stage barrier, fast-math build_tab) with 2 CELLS/THREAD
// interleaved (TPB=256, window 512): halves wave-stages/CU -> DS issue and
// barrier-convoy participants halve at constant total VALU work; per-thread
// x/y dual chains replace the lost second wave's TLP. Scalar-style code
// (no vector types / lambdas) to avoid the R8 spill pathology.
// Per-cell arithmetic identical to R20/R21 -> absmax must stay 131072.

constexpr int TPB     = 256;
constexpr int WIN     = 512;               // 2 cells/thread
constexpr int S_FUSE  = 32;
constexpr int HALO    = 4 * S_FUSE;        // 128
constexpr int B_INNER = WIN - 2 * HALO;    // 256

constexpr int   NTAB   = 5633;             // nodes: u in [-22,22], h = 1/128
constexpr float VSLOPE = 88.72283911167299f;  // ln2 * 128
constexpr float VOFF   = 2816.0f;             // -U_MIN * 128
constexpr float HSTEP  = 0.0078125f;          // h = 1/128
constexpr int   NSEG   = NTAB - 1;            // 5632 float4 segments

// float-layout of d_ws / LDS:
//   [0 .. 4*NSEG)        float4 tab4[i] = (v_i, d_i, v_{i+1}, d_{i+1})
//   [4*NSEG]             scale = 10^p_exp
//   [4*NSEG+1 .. +32]    A[s] = (t[s+1]-t[s]) * 0.3125f
constexpr int F_SCALE = 4 * NSEG;          // 22528
constexpr int F_A0    = 4 * NSEG + 1;      // 22529
constexpr int F_TOT   = 4 * NSEG + 1 + 32; // 22561
constexpr int F4_TOT  = (F_TOT + 3) / 4;   // 5641 float4s staged

__device__ __forceinline__ float fast_tanh(float x) {
    float e = __expf(2.0f * x);
    return 1.0f - 2.0f * __builtin_amdgcn_rcpf(1.0f + e);
}

// ---------- prep: build ret table (value + d/du), duplicated-pair layout ----
__global__ __launch_bounds__(256)
void build_tab_kernel(const float* __restrict__ W1, const float* __restrict__ b1,
                      const float* __restrict__ W2, const float* __restrict__ b2,
                      const float* __restrict__ W3, const float* __restrict__ b3,
                      const float* __restrict__ W4, const float* __restrict__ b4,
                      const float* __restrict__ p_exp, const float* __restrict__ t,
                      int nsteps, float* __restrict__ wsf)
{
    const int i = blockIdx.x * blockDim.x + threadIdx.x;
    if (i > NTAB) {
        const int s = i - NTAB - 1;          // aux: A[s]
        if (s < nsteps && s < 32)
            wsf[F_A0 + s] = (t[s + 1] - t[s]) * 0.3125f;
        return;
    }
    if (i == NTAB) {                          // aux: scale
        wsf[F_SCALE] = powf(10.0f, p_exp[0]);
        return;
    }
    const float u  = -22.0f + (float)i * HSTEP;
    const float y  = sinhf(u);     // MLP input at this node
    const float yd = coshf(u);     // dy/du

    float h[15], hd[15], g[15], gd[15];
#pragma unroll
    for (int j = 0; j < 15; ++j) {
        float a  = fmaf(y, W1[j], b1[j]);
        float ad = yd * W1[j];
        float th = fast_tanh(a);
        h[j]  = th;
        hd[j] = (1.0f - th * th) * ad;
    }
#pragma unroll
    for (int j = 0; j < 15; ++j) {
        float a = b2[j], ad = 0.0f;
#pragma unroll
        for (int k = 0; k < 15; ++k) {
            a  = fmaf(h[k],  W2[k * 15 + j], a);
            ad = fmaf(hd[k], W2[k * 15 + j], ad);
        }
        float th = fast_tanh(a);
        g[j]  = th;
        gd[j] = (1.0f - th * th) * ad;
    }
#pragma unroll
    for (int j = 0; j < 15; ++j) {
        float a = b3[j], ad = 0.0f;
#pragma unroll
        for (int k = 0; k < 15; ++k) {
            a  = fmaf(g[k],  W3[k * 15 + j], a);
            ad = fmaf(gd[k], W3[k * 15 + j], ad);
        }
        float th = fast_tanh(a);
        h[j]  = th;
        hd[j] = (1.0f - th * th) * ad;
    }
    float o = b4[0], od = 0.0f;
#pragma unroll
    for (int k = 0; k < 15; ++k) {
        o  = fmaf(h[k],  W4[k], o);
        od = fmaf(hd[k], W4[k], od);
    }
    const float s = __builtin_amdgcn_rcpf(1.0f + __expf(-o));   // sigmoid
    const float d = s * (1.0f - s) * od;
    if (i < NSEG) {
        wsf[4 * i]     = s;       // tab4[i].x = v_i
        wsf[4 * i + 1] = d;       // tab4[i].y = d_i
    }
    if (i > 0) {
        wsf[4 * (i - 1) + 2] = s; // tab4[i-1].z = v_i
        wsf[4 * (i - 1) + 3] = d; // tab4[i-1].w = d_i
    }
}

// ---------- table evaluation: one ds_read_b128 + cubic Hermite --------------
__device__ __forceinline__ float ret_tab(float c, float scale,
                                         const float4* __restrict__ tab4)
{
    const float y  = c * scale;
    const float ay = fabsf(y);
    const float w  = ay + __builtin_amdgcn_sqrtf(fmaf(ay, ay, 1.0f));
    const float m  = copysignf(VSLOPE, y);
    float v = fmaf(__builtin_amdgcn_logf(w), m, VOFF);
    v = fminf(fmaxf(v, 0.0f), (float)(NSEG - 1) + 0.999f);  // clamp to table
    const int   i   = (int)v;
    const float tau = v - (float)i;

    const float4 AB = tab4[i];       // (v_i, d_i, v_{i+1}, d_{i+1})
    const float t2 = tau * tau;
    const float t3 = t2 * tau;
    return AB.x * (2.0f * t3 - 3.0f * t2 + 1.0f)
         + AB.z * (3.0f * t2 - 2.0f * t3)
         + HSTEP * (AB.y * (t3 - 2.0f * t2 + tau) + AB.w * (t3 - t2));
}

// LDS-only barrier (R21-validated): drain lgkmcnt but NOT vmcnt.
#define STAGE_BARRIER()                                            \
    do {                                                           \
        __builtin_amdgcn_sched_barrier(0);                         \
        asm volatile("s_waitcnt lgkmcnt(0)\n\ts_barrier" ::: "memory"); \
        __builtin_amdgcn_sched_barrier(0);                         \
    } while (0)

__global__ __launch_bounds__(TPB)
void rk4_steps_kernel(const float* __restrict__ src,   // state at step s0 [N]
                      float* __restrict__ out,         // [T, N]
                      const float* __restrict__ wsf,   // table+aux in d_ws
                      int N, int s0, int nsub)
{
    __shared__ float tlds[F4_TOT * 4];   // table + aux (~90KB)
    __shared__ float la[WIN];
    __shared__ float lb[WIN];

    const int tid = threadIdx.x;

    // stage table+aux, float4-vectorized
    {
        const float4* __restrict__ s4 = (const float4*)wsf;
        float4* d4 = (float4*)tlds;
        for (int i = tid; i < F4_TOT; i += TPB) d4[i] = s4[i];
    }

    const int base = blockIdx.x * B_INNER - HALO;   // even
    const int w0   = 2 * tid;                        // even window cell
    const int g0   = base + w0;                      // even global cell
    const int g1   = g0 + 1;                         // odd global cell

    float cx = src[min(max(g0, 0), N - 1)];
    float cy = src[min(max(g1, 0), N - 1)];

    // clamped neighbor indices (R8-validated pattern; edge garbage -> halo)
    const int iu = max(w0 - 1, 0);          // left neighbor of even cell
    const int id = min(w0 + 2, WIN - 1);    // right neighbor of odd cell

    // valid window cells [HALO, HALO+B_INNER) = [128, 384) -> tid in [64,192)
    const bool valid = (w0 >= HALO) && (w0 < HALO + B_INNER);

    if (s0 == 0 && valid && (unsigned)g0 < (unsigned)N - 1) {
        *(float2*)(out + g0) = make_float2(cx, cy);   // row 0 (8B-aligned)
    }

    __syncthreads();                  // table staged (full barrier, one-time)
    const float4* __restrict__ tab4 = (const float4*)tlds;
    const float scale = tlds[F_SCALE];

    for (int s = 0; s < nsub; ++s) {
        const float A = tlds[F_A0 + s];   // uniform broadcast, dt*D0

        // ---- stage 1 ----
        float r1x = ret_tab(cx, scale, tab4);
        float r1y = ret_tab(cy, scale, tab4);
        *(float2*)(la + w0) = make_float2(cx, cy);    // one ds_write_b64
        STAGE_BARRIER();
        float lft = la[iu], rgt = la[id];
        float k1x, k1y;
        if (g0 == 0)          k1x = r1x * ((1.0f - cx) + (cy - cx));
        else                  k1x = r1x * (lft + cy - 2.0f * cx);
        if (g1 == N - 1)      k1y = r1y * ((cx - cy) + (0.0125f * (cx - cy) - cy));
        else                  k1y = r1y * (cx + rgt - 2.0f * cy);
        float c2x = fmaf(0.5f * A, k1x, cx);
        float c2y = fmaf(0.5f * A, k1y, cy);

        // ---- stage 2 ----
        float r2x = ret_tab(c2x, scale, tab4);
        float r2y = ret_tab(c2y, scale, tab4);
        *(float2*)(lb + w0) = make_float2(c2x, c2y);
        STAGE_BARRIER();
        lft = lb[iu]; rgt = lb[id];
        float k2x, k2y;
        if (g0 == 0)          k2x = r2x * ((1.0f - c2x) + (c2y - c2x));
        else                  k2x = r2x * (lft + c2y - 2.0f * c2x);
        if (g1 == N - 1)      k2y = r2y * ((c2x - c2y) + (0.0125f * (c2x - c2y) - c2y));
        else                  k2y = r2y * (c2x + rgt - 2.0f * c2y);
        float c3x = fmaf(0.5f * A, k2x, cx);
        float c3y = fmaf(0.5f * A, k2y, cy);

        // ---- stage 3 ----
        float r3x = ret_tab(c3x, scale, tab4);
        float r3y = ret_tab(c3y, scale, tab4);
        *(float2*)(la + w0) = make_float2(c3x, c3y);
        STAGE_BARRIER();
        lft = la[iu]; rgt = la[id];
        float k3x, k3y;
        if (g0 == 0)          k3x = r3x * ((1.0f - c3x) + (c3y - c3x));
        else                  k3x = r3x * (lft + c3y - 2.0f * c3x);
        if (g1 == N - 1)      k3y = r3y * ((c3x - c3y) + (0.0125f * (c3x - c3y) - c3y));
        else                  k3y = r3y * (c3x + rgt - 2.0f * c3y);
        float c4x = fmaf(A, k3x, cx);
        float c4y = fmaf(A, k3y, cy);

        // ---- stage 4 ----
        float r4x = ret_tab(c4x, scale, tab4);
        float r4y = ret_tab(c4y, scale, tab4);
        *(float2*)(lb + w0) = make_float2(c4x, c4y);
        STAGE_BARRIER();
        lft = lb[iu]; rgt = lb[id];
        float k4x, k4y;
        if (g0 == 0)          k4x = r4x * ((1.0f - c4x) + (c4y - c4x));
        else                  k4x = r4x * (lft + c4y - 2.0f * c4x);
        if (g1 == N - 1)      k4y = r4y * ((c4x - c4y) + (0.0125f * (c4x - c4y) - c4y));
        else                  k4y = r4y * (c4x + rgt - 2.0f * c4y);

        cx = fmaf(A * (1.0f / 6.0f), k1x + 2.0f * (k2x + k3x) + k4x, cx);
        cy = fmaf(A * (1.0f / 6.0f), k1y + 2.0f * (k2y + k3y) + k4y, cy);

        // write valid inner window (background store, 8B-aligned float2)
        if (valid && (unsigned)g0 < (unsigned)N - 1) {
            float* row = out + (size_t)(s0 + s + 1) * N;
            *(float2*)(row + g0) = make_float2(cx, cy);
        }
    }
}

extern "C" void kernel_launch(void* const* d_in, const int* in_sizes, int n_in,
                              void* d_out, int out_size, void* d_ws, size_t ws_size,
                              hipStream_t stream)
{
    const float* c0    = (const float*)d_in[0];
    const float* t     = (const float*)d_in[1];
    const float* W1    = (const float*)d_in[2];
    const float* b1    = (const float*)d_in[3];
    const float* W2    = (const float*)d_in[4];
    const float* b2    = (const float*)d_in[5];
    const float* W3    = (const float*)d_in[6];
    const float* b3    = (const float*)d_in[7];
    const float* W4    = (const float*)d_in[8];
    const float* b4    = (const float*)d_in[9];
    const float* p_exp = (const float*)d_in[10];

    float* out = (float*)d_out;
    float* wsf = (float*)d_ws;   // F_TOT floats = 90244 B

    const int N      = in_sizes[0];       // 65536
    const int nsteps = in_sizes[1] - 1;   // 32

    // build ret table + aux (scale, A[s])
    const int tgrid = (NTAB + 1 + 32 + 255) / 256;
    hipLaunchKernelGGL(build_tab_kernel, dim3(tgrid), dim3(256), 0, stream,
                       W1, b1, W2, b2, W3, b3, W4, b4, p_exp, t, nsteps, wsf);

    const int grid = (N + B_INNER - 1) / B_INNER;  // 256 -> 1 block/CU

    for (int s0 = 0; s0 < nsteps; s0 += S_FUSE) {   // single iteration for T=33
        const int nsub = min(S_FUSE, nsteps - s0);
        const float* src = (s0 == 0) ? c0 : out + (size_t)s0 * N;
        hipLaunchKernelGGL(rk4_steps_kernel, dim3(grid), dim3(TPB), 0, stream,
                           src, out, wsf, N, s0, nsub);
    }
}

// Round 23
// 46.914 us; speedup vs baseline: 1.2083x; 1.2083x over previous
//
#include <hip/hip_runtime.h>
#include <math.h>

// ConcentrationPredictor: 32 RK4 steps of dc/dt = flux(c), per-cell MLP D_eff.
// R23 = R21 (single rk4 dispatch, TPB=512, inner 256, grid 256 = 1 block/CU,
// 8 waves = 2/SIMD [R22 proved 1/SIMD loses], one ds_read_b128 per eval,
// hoisted gathers, LDS A[s], sentinel halo buffers, lgkm-only raw stage
// barrier, fast-math build_tab) with the table stored as MONOMIAL CUBIC
// COEFFICIENTS per segment: tab4[i] = (a0, a1, a2, a3) so evaluation after
// the load is 3 nested FMAs instead of ~12 Hermite-basis ops. Same
// polynomial algebraically; build_tab computes both segment endpoints
// (recompute, no extra dispatch).

constexpr int TPB     = 512;
constexpr int S_FUSE  = 32;
constexpr int HALO    = 4 * S_FUSE;        // 128
constexpr int B_INNER = TPB - 2 * HALO;    // 256

constexpr int   NTAB   = 5633;             // nodes: u in [-22,22], h = 1/128
constexpr float VSLOPE = 88.72283911167299f;  // ln2 * 128
constexpr float VOFF   = 2816.0f;             // -U_MIN * 128
constexpr float HSTEP  = 0.0078125f;          // h = 1/128
constexpr int   NSEG   = NTAB - 1;            // 5632 cubic segments

// float-layout of d_ws / LDS:
//   [0 .. 4*NSEG)        float4 tab4[i] = (a0, a1, a2, a3) monomial coefs
//   [4*NSEG]             scale = 10^p_exp
//   [4*NSEG+1 .. +32]    A[s] = (t[s+1]-t[s]) * 0.3125f
constexpr int F_SCALE = 4 * NSEG;          // 22528
constexpr int F_A0    = 4 * NSEG + 1;      // 22529
constexpr int F_TOT   = 4 * NSEG + 1 + 32; // 22561
constexpr int F4_TOT  = (F_TOT + 3) / 4;   // 5641 float4s staged

__device__ __forceinline__ float fast_tanh(float x) {
    float e = __expf(2.0f * x);
    return 1.0f - 2.0f * __builtin_amdgcn_rcpf(1.0f + e);
}

// value + d/du of ret at table node idx (u = -22 + idx*h)
__device__ void mlp_node(int idx,
                         const float* __restrict__ W1, const float* __restrict__ b1,
                         const float* __restrict__ W2, const float* __restrict__ b2,
                         const float* __restrict__ W3, const float* __restrict__ b3,
                         const float* __restrict__ W4, const float* __restrict__ b4,
                         float& sv, float& dv)
{
    const float u  = -22.0f + (float)idx * HSTEP;
    const float y  = sinhf(u);
    const float yd = coshf(u);

    float h[15], hd[15], g[15], gd[15];
#pragma unroll
    for (int j = 0; j < 15; ++j) {
        float a  = fmaf(y, W1[j], b1[j]);
        float ad = yd * W1[j];
        float th = fast_tanh(a);
        h[j]  = th;
        hd[j] = (1.0f - th * th) * ad;
    }
#pragma unroll
    for (int j = 0; j < 15; ++j) {
        float a = b2[j], ad = 0.0f;
#pragma unroll
        for (int k = 0; k < 15; ++k) {
            a  = fmaf(h[k],  W2[k * 15 + j], a);
            ad = fmaf(hd[k], W2[k * 15 + j], ad);
        }
        float th = fast_tanh(a);
        g[j]  = th;
        gd[j] = (1.0f - th * th) * ad;
    }
#pragma unroll
    for (int j = 0; j < 15; ++j) {
        float a = b3[j], ad = 0.0f;
#pragma unroll
        for (int k = 0; k < 15; ++k) {
            a  = fmaf(g[k],  W3[k * 15 + j], a);
            ad = fmaf(gd[k], W3[k * 15 + j], ad);
        }
        float th = fast_tanh(a);
        h[j]  = th;
        hd[j] = (1.0f - th * th) * ad;
    }
    float o = b4[0], od = 0.0f;
#pragma unroll
    for (int k = 0; k < 15; ++k) {
        o  = fmaf(h[k],  W4[k], o);
        od = fmaf(hd[k], W4[k], od);
    }
    const float s = __builtin_amdgcn_rcpf(1.0f + __expf(-o));   // sigmoid
    sv = s;
    dv = s * (1.0f - s) * od;
}

// ---------- prep: build monomial-coefficient table ----------
__global__ __launch_bounds__(256)
void build_tab_kernel(const float* __restrict__ W1, const float* __restrict__ b1,
                      const float* __restrict__ W2, const float* __restrict__ b2,
                      const float* __restrict__ W3, const float* __restrict__ b3,
                      const float* __restrict__ W4, const float* __restrict__ b4,
                      const float* __restrict__ p_exp, const float* __restrict__ t,
                      int nsteps, float* __restrict__ wsf)
{
    const int i = blockIdx.x * blockDim.x + threadIdx.x;
    if (i > NSEG) {
        const int s = i - NSEG - 1;          // aux: A[s]
        if (s < nsteps && s < 32)
            wsf[F_A0 + s] = (t[s + 1] - t[s]) * 0.3125f;
        return;
    }
    if (i == NSEG) {                          // aux: scale
        wsf[F_SCALE] = powf(10.0f, p_exp[0]);
        return;
    }
    float v0, d0, v1, d1;
    mlp_node(i,     W1, b1, W2, b2, W3, b3, W4, b4, v0, d0);
    mlp_node(i + 1, W1, b1, W2, b2, W3, b3, W4, b4, v1, d1);

    // cubic Hermite -> monomial in tau (segment length h folded into derivs)
    const float hd0 = HSTEP * d0;
    const float hd1 = HSTEP * d1;
    const float dl  = v1 - v0;
    wsf[4 * i]     = v0;                                 // a0
    wsf[4 * i + 1] = hd0;                                // a1
    wsf[4 * i + 2] = 3.0f * dl - 2.0f * hd0 - hd1;       // a2
    wsf[4 * i + 3] = -2.0f * dl + hd0 + hd1;             // a3
}

// ---------- table evaluation: one ds_read_b128 + 3 nested FMAs --------------
__device__ __forceinline__ float ret_tab(float c, float scale,
                                         const float4* __restrict__ tab4)
{
    const float y  = c * scale;
    const float ay = fabsf(y);
    // u = asinh(y); v = (u + 22)*128 folded into one fma off v_log_f32 (log2)
    const float w  = ay + __builtin_amdgcn_sqrtf(fmaf(ay, ay, 1.0f));
    const float m  = copysignf(VSLOPE, y);
    float v = fmaf(__builtin_amdgcn_logf(w), m, VOFF);
    v = fminf(fmaxf(v, 0.0f), (float)(NSEG - 1) + 0.999f);  // clamp to table
    const int   i   = (int)v;
    const float tau = v - (float)i;

    const float4 A = tab4[i];        // (a0, a1, a2, a3)
    return fmaf(fmaf(fmaf(A.w, tau, A.z), tau, A.y), tau, A.x);
}

// flux/D0 (D0 folded into the A coefficient)
__device__ __forceinline__ float flux_cell(float ret, float c, float cl, float cr,
                                           int g, int N)
{
    if (g == 0)
        return ret * ((1.0f - c) + (cr - c));
    if (g == N - 1) {
        float rbc = 0.0125f * (cl - c);   // D0*DX*(c[N-2]-c[N-1])
        return ret * ((cl - c) + (rbc - c));
    }
    return ret * (cl + cr - 2.0f * c);
}

// LDS-only barrier (R21-validated): drain lgkmcnt but NOT vmcnt, so output
// stores retire in the background.
#define STAGE_BARRIER()                                            \
    do {                                                           \
        __builtin_amdgcn_sched_barrier(0);                         \
        asm volatile("s_waitcnt lgkmcnt(0)\n\ts_barrier" ::: "memory"); \
        __builtin_amdgcn_sched_barrier(0);                         \
    } while (0)

__global__ __launch_bounds__(TPB)
void rk4_steps_kernel(const float* __restrict__ src,   // state at step s0 [N]
                      float* __restrict__ out,         // [T, N]
                      const float* __restrict__ wsf,   // table+aux in d_ws
                      int N, int s0, int nsub)
{
    __shared__ float tlds[F4_TOT * 4];   // table + aux (~90KB)
    __shared__ float la[TPB + 2];        // sentinel slots [0] and [TPB+1]
    __shared__ float lb[TPB + 2];

    const int tid = threadIdx.x;

    // stage table+aux, float4-vectorized
    {
        const float4* __restrict__ s4 = (const float4*)wsf;
        float4* d4 = (float4*)tlds;
        for (int i = tid; i < F4_TOT; i += TPB) d4[i] = s4[i];
    }

    const int g  = blockIdx.x * B_INNER - HALO + tid;  // my global cell (may be OOB)
    const int gi = min(max(g, 0), N - 1);              // clamped load index

    float c = src[gi];

    const bool valid = (tid >= HALO) && (tid < HALO + B_INNER) && (g < N);

    // single launch also writes row 0 (replaces the D2D memcpy)
    if (s0 == 0 && valid) out[g] = c;

    __syncthreads();                  // table staged (full barrier, one-time)
    const float4* __restrict__ tab4 = (const float4*)tlds;
    const float scale = tlds[F_SCALE];

    for (int s = 0; s < nsub; ++s) {
        const float A = tlds[F_A0 + s];   // uniform broadcast, dt*D0

        // stage 1: gather hoisted above write+barrier (latency folds into
        // the barrier's lgkmcnt wait)
        float ret1 = ret_tab(c, scale, tab4);
        la[tid + 1] = c;
        STAGE_BARRIER();
        float cl = la[tid], cr = la[tid + 2];
        float k1 = flux_cell(ret1, c, cl, cr, g, N);
        float c2 = fmaf(0.5f * A, k1, c);

        // stage 2
        float ret2 = ret_tab(c2, scale, tab4);
        lb[tid + 1] = c2;
        STAGE_BARRIER();
        cl = lb[tid]; cr = lb[tid + 2];
        float k2 = flux_cell(ret2, c2, cl, cr, g, N);
        float c3 = fmaf(0.5f * A, k2, c);

        // stage 3
        float ret3 = ret_tab(c3, scale, tab4);
        la[tid + 1] = c3;
        STAGE_BARRIER();
        cl = la[tid]; cr = la[tid + 2];
        float k3 = flux_cell(ret3, c3, cl, cr, g, N);
        float c4 = fmaf(A, k3, c);

        // stage 4
        float ret4 = ret_tab(c4, scale, tab4);
        lb[tid + 1] = c4;
        STAGE_BARRIER();
        cl = lb[tid]; cr = lb[tid + 2];
        float k4 = flux_cell(ret4, c4, cl, cr, g, N);

        c = fmaf(A * (1.0f / 6.0f), k1 + 2.0f * (k2 + k3) + k4, c);

        // write valid inner window (store retires in the background)
        if (valid)
            out[(size_t)(s0 + s + 1) * N + g] = c;
    }
}

extern "C" void kernel_launch(void* const* d_in, const int* in_sizes, int n_in,
                              void* d_out, int out_size, void* d_ws, size_t ws_size,
                              hipStream_t stream)
{
    const float* c0    = (const float*)d_in[0];
    const float* t     = (const float*)d_in[1];
    const float* W1    = (const float*)d_in[2];
    const float* b1    = (const float*)d_in[3];
    const float* W2    = (const float*)d_in[4];
    const float* b2    = (const float*)d_in[5];
    const float* W3    = (const float*)d_in[6];
    const float* b3    = (const float*)d_in[7];
    const float* W4    = (const float*)d_in[8];
    const float* b4    = (const float*)d_in[9];
    const float* p_exp = (const float*)d_in[10];

    float* out = (float*)d_out;
    float* wsf = (float*)d_ws;   // F_TOT floats = 90244 B

    const int N      = in_sizes[0];       // 65536
    const int nsteps = in_sizes[1] - 1;   // 32

    // build coefficient table + aux (scale, A[s])
    const int tgrid = (NSEG + 1 + 32 + 255) / 256;
    hipLaunchKernelGGL(build_tab_kernel, dim3(tgrid), dim3(256), 0, stream,
                       W1, b1, W2, b2, W3, b3, W4, b4, p_exp, t, nsteps, wsf);

    const int grid = (N + B_INNER - 1) / B_INNER;  // 256 -> 1 block/CU

    for (int s0 = 0; s0 < nsteps; s0 += S_FUSE) {   // single iteration for T=33
        const int nsub = min(S_FUSE, nsteps - s0);
        const float* src = (s0 == 0) ? c0 : out + (size_t)s0 * N;
        hipLaunchKernelGGL(rk4_steps_kernel, dim3(grid), dim3(TPB), 0, stream,
                           src, out, wsf, N, s0, nsub);
    }
}

// Round 24
// 46.370 us; speedup vs baseline: 1.2225x; 1.0117x over previous
//
#include <hip/hip_runtime.h>
#include <math.h>

// ConcentrationPredictor: 32 RK4 steps of dc/dt = flux(c), per-cell MLP D_eff.
// R24 = FINAL: exact revert to R21, the measured-best configuration.
//  - Single rk4 dispatch: TPB=512, inner 256, grid 256 = 1 block/CU,
//    8 waves = 2/SIMD (R22 proved 1/SIMD loses; R13/R15 proved 2 blocks/CU
//    loses at this redundancy).
//  - ret(y) as asinh-space cubic-Hermite table, duplicated-pair float4
//    layout -> ONE ds_read_b128 per evaluation (R20: conflicts 4.09M->2.07M,
//    rk4 42.8->38.6us).
//  - gathers hoisted above each stage's halo write+barrier (latency folds
//    into the barrier's lgkmcnt wait, R14).
//  - lgkm-only raw stage barrier (R21: output stores retire in background;
//    proven race-free, absmax bit-stable at 131072).
//  - A[s] = dt*D0 precomputed to LDS; fast-math build_tab (R18/R19).
// Basin mapping R13-R23: all other structural variants measured neutral or
// worse. Remaining time = 128 algorithmically-serial RK4 stages x ~300cyc
// cross-thread exchange chain + fixed harness overhead.

constexpr int TPB     = 512;
constexpr int S_FUSE  = 32;
constexpr int HALO    = 4 * S_FUSE;        // 128
constexpr int B_INNER = TPB - 2 * HALO;    // 256

constexpr int   NTAB   = 5633;             // nodes: u in [-22,22], h = 1/128
constexpr float VSLOPE = 88.72283911167299f;  // ln2 * 128
constexpr float VOFF   = 2816.0f;             // -U_MIN * 128
constexpr float HSTEP  = 0.0078125f;          // h = 1/128
constexpr int   NSEG   = NTAB - 1;            // 5632 float4 segments

// float-layout of d_ws / LDS:
//   [0 .. 4*NSEG)        float4 tab4[i] = (v_i, d_i, v_{i+1}, d_{i+1})
//   [4*NSEG]             scale = 10^p_exp
//   [4*NSEG+1 .. +32]    A[s] = (t[s+1]-t[s]) * 0.3125f
constexpr int F_SCALE = 4 * NSEG;          // 22528
constexpr int F_A0    = 4 * NSEG + 1;      // 22529
constexpr int F_TOT   = 4 * NSEG + 1 + 32; // 22561
constexpr int F4_TOT  = (F_TOT + 3) / 4;   // 5641 float4s staged

__device__ __forceinline__ float fast_tanh(float x) {
    float e = __expf(2.0f * x);
    return 1.0f - 2.0f * __builtin_amdgcn_rcpf(1.0f + e);
}

// ---------- prep: build ret table (value + d/du), duplicated-pair layout ----
__global__ __launch_bounds__(256)
void build_tab_kernel(const float* __restrict__ W1, const float* __restrict__ b1,
                      const float* __restrict__ W2, const float* __restrict__ b2,
                      const float* __restrict__ W3, const float* __restrict__ b3,
                      const float* __restrict__ W4, const float* __restrict__ b4,
                      const float* __restrict__ p_exp, const float* __restrict__ t,
                      int nsteps, float* __restrict__ wsf)
{
    const int i = blockIdx.x * blockDim.x + threadIdx.x;
    if (i > NTAB) {
        const int s = i - NTAB - 1;          // aux: A[s]
        if (s < nsteps && s < 32)
            wsf[F_A0 + s] = (t[s + 1] - t[s]) * 0.3125f;
        return;
    }
    if (i == NTAB) {                          // aux: scale
        wsf[F_SCALE] = powf(10.0f, p_exp[0]);
        return;
    }
    const float u  = -22.0f + (float)i * HSTEP;
    const float y  = sinhf(u);     // MLP input at this node
    const float yd = coshf(u);     // dy/du

    float h[15], hd[15], g[15], gd[15];
#pragma unroll
    for (int j = 0; j < 15; ++j) {
        float a  = fmaf(y, W1[j], b1[j]);
        float ad = yd * W1[j];
        float th = fast_tanh(a);
        h[j]  = th;
        hd[j] = (1.0f - th * th) * ad;
    }
#pragma unroll
    for (int j = 0; j < 15; ++j) {
        float a = b2[j], ad = 0.0f;
#pragma unroll
        for (int k = 0; k < 15; ++k) {
            a  = fmaf(h[k],  W2[k * 15 + j], a);
            ad = fmaf(hd[k], W2[k * 15 + j], ad);
        }
        float th = fast_tanh(a);
        g[j]  = th;
        gd[j] = (1.0f - th * th) * ad;
    }
#pragma unroll
    for (int j = 0; j < 15; ++j) {
        float a = b3[j], ad = 0.0f;
#pragma unroll
        for (int k = 0; k < 15; ++k) {
            a  = fmaf(g[k],  W3[k * 15 + j], a);
            ad = fmaf(gd[k], W3[k * 15 + j], ad);
        }
        float th = fast_tanh(a);
        h[j]  = th;
        hd[j] = (1.0f - th * th) * ad;
    }
    float o = b4[0], od = 0.0f;
#pragma unroll
    for (int k = 0; k < 15; ++k) {
        o  = fmaf(h[k],  W4[k], o);
        od = fmaf(hd[k], W4[k], od);
    }
    const float s = __builtin_amdgcn_rcpf(1.0f + __expf(-o));   // sigmoid
    const float d = s * (1.0f - s) * od;
    // duplicated-pair layout: node i is the left end of segment i and the
    // right end of segment i-1
    if (i < NSEG) {
        wsf[4 * i]     = s;       // tab4[i].x = v_i
        wsf[4 * i + 1] = d;       // tab4[i].y = d_i
    }
    if (i > 0) {
        wsf[4 * (i - 1) + 2] = s; // tab4[i-1].z = v_i
        wsf[4 * (i - 1) + 3] = d; // tab4[i-1].w = d_i
    }
}

// ---------- table evaluation: one ds_read_b128 + cubic Hermite --------------
__device__ __forceinline__ float ret_tab(float c, float scale,
                                         const float4* __restrict__ tab4)
{
    const float y  = c * scale;
    const float ay = fabsf(y);
    // u = asinh(y); v = (u + 22)*128 folded into one fma off v_log_f32 (log2)
    const float w  = ay + __builtin_amdgcn_sqrtf(fmaf(ay, ay, 1.0f));
    const float m  = copysignf(VSLOPE, y);
    float v = fmaf(__builtin_amdgcn_logf(w), m, VOFF);
    v = fminf(fmaxf(v, 0.0f), (float)(NSEG - 1) + 0.999f);  // clamp to table
    const int   i   = (int)v;
    const float tau = v - (float)i;

    const float4 AB = tab4[i];       // (v_i, d_i, v_{i+1}, d_{i+1})
    const float t2 = tau * tau;
    const float t3 = t2 * tau;
    return AB.x * (2.0f * t3 - 3.0f * t2 + 1.0f)
         + AB.z * (3.0f * t2 - 2.0f * t3)
         + HSTEP * (AB.y * (t3 - 2.0f * t2 + tau) + AB.w * (t3 - t2));
}

// flux/D0 (D0 folded into the A coefficient)
__device__ __forceinline__ float flux_cell(float ret, float c, float cl, float cr,
                                           int g, int N)
{
    if (g == 0)
        return ret * ((1.0f - c) + (cr - c));
    if (g == N - 1) {
        float rbc = 0.0125f * (cl - c);   // D0*DX*(c[N-2]-c[N-1])
        return ret * ((cl - c) + (rbc - c));
    }
    return ret * (cl + cr - 2.0f * c);
}

// LDS-only barrier: drain lgkmcnt (LDS writes/reads) but NOT vmcnt, so the
// per-stage output stores retire in the background instead of stalling the
// convoy. Memory clobber orders surrounding LDS ops; sched_barrier(0) stops
// the machine scheduler hoisting post-barrier ds_reads (guide rule #18).
#define STAGE_BARRIER()                                            \
    do {                                                           \
        __builtin_amdgcn_sched_barrier(0);                         \
        asm volatile("s_waitcnt lgkmcnt(0)\n\ts_barrier" ::: "memory"); \
        __builtin_amdgcn_sched_barrier(0);                         \
    } while (0)

__global__ __launch_bounds__(TPB)
void rk4_steps_kernel(const float* __restrict__ src,   // state at step s0 [N]
                      float* __restrict__ out,         // [T, N]
                      const float* __restrict__ wsf,   // table+aux in d_ws
                      int N, int s0, int nsub)
{
    __shared__ float tlds[F4_TOT * 4];   // table + aux (float4-staged, ~90KB)
    __shared__ float la[TPB + 2];        // sentinel slots [0] and [TPB+1]
    __shared__ float lb[TPB + 2];

    const int tid = threadIdx.x;

    // stage table+aux, float4-vectorized
    {
        const float4* __restrict__ s4 = (const float4*)wsf;
        float4* d4 = (float4*)tlds;
        for (int i = tid; i < F4_TOT; i += TPB) d4[i] = s4[i];
    }

    const int g  = blockIdx.x * B_INNER - HALO + tid;  // my global cell (may be OOB)
    const int gi = min(max(g, 0), N - 1);              // clamped load index

    float c = src[gi];

    const bool valid = (tid >= HALO) && (tid < HALO + B_INNER) && (g < N);

    // single launch also writes row 0 (replaces the D2D memcpy)
    if (s0 == 0 && valid) out[g] = c;

    __syncthreads();                  // table staged (full barrier, one-time)
    const float4* __restrict__ tab4 = (const float4*)tlds;
    const float scale = tlds[F_SCALE];

    for (int s = 0; s < nsub; ++s) {
        const float A = tlds[F_A0 + s];   // uniform broadcast, dt*D0

        // stage 1: gather hoisted above write+barrier (latency folds into
        // the barrier's lgkmcnt wait)
        float ret1 = ret_tab(c, scale, tab4);
        la[tid + 1] = c;
        STAGE_BARRIER();
        float cl = la[tid], cr = la[tid + 2];
        float k1 = flux_cell(ret1, c, cl, cr, g, N);
        float c2 = fmaf(0.5f * A, k1, c);

        // stage 2
        float ret2 = ret_tab(c2, scale, tab4);
        lb[tid + 1] = c2;
        STAGE_BARRIER();
        cl = lb[tid]; cr = lb[tid + 2];
        float k2 = flux_cell(ret2, c2, cl, cr, g, N);
        float c3 = fmaf(0.5f * A, k2, c);

        // stage 3
        float ret3 = ret_tab(c3, scale, tab4);
        la[tid + 1] = c3;
        STAGE_BARRIER();
        cl = la[tid]; cr = la[tid + 2];
        float k3 = flux_cell(ret3, c3, cl, cr, g, N);
        float c4 = fmaf(A, k3, c);

        // stage 4
        float ret4 = ret_tab(c4, scale, tab4);
        lb[tid + 1] = c4;
        STAGE_BARRIER();
        cl = lb[tid]; cr = lb[tid + 2];
        float k4 = flux_cell(ret4, c4, cl, cr, g, N);

        c = fmaf(A * (1.0f / 6.0f), k1 + 2.0f * (k2 + k3) + k4, c);

        // write valid inner window of this step's new state (store retires
        // in the background; no barrier ever waits on vmcnt)
        if (valid)
            out[(size_t)(s0 + s + 1) * N + g] = c;
    }
}

extern "C" void kernel_launch(void* const* d_in, const int* in_sizes, int n_in,
                              void* d_out, int out_size, void* d_ws, size_t ws_size,
                              hipStream_t stream)
{
    const float* c0    = (const float*)d_in[0];
    const float* t     = (const float*)d_in[1];
    const float* W1    = (const float*)d_in[2];
    const float* b1    = (const float*)d_in[3];
    const float* W2    = (const float*)d_in[4];
    const float* b2    = (const float*)d_in[5];
    const float* W3    = (const float*)d_in[6];
    const float* b3    = (const float*)d_in[7];
    const float* W4    = (const float*)d_in[8];
    const float* b4    = (const float*)d_in[9];
    const float* p_exp = (const float*)d_in[10];

    float* out = (float*)d_out;
    float* wsf = (float*)d_ws;   // F_TOT floats = 90244 B

    const int N      = in_sizes[0];       // 65536
    const int nsteps = in_sizes[1] - 1;   // 32

    // build ret table + aux (scale, A[s])
    const int tgrid = (NTAB + 1 + 32 + 255) / 256;
    hipLaunchKernelGGL(build_tab_kernel, dim3(tgrid), dim3(256), 0, stream,
                       W1, b1, W2, b2, W3, b3, W4, b4, p_exp, t, nsteps, wsf);

    const int grid = (N + B_INNER - 1) / B_INNER;  // 256 -> 1 block/CU

    for (int s0 = 0; s0 < nsteps; s0 += S_FUSE) {   // single iteration for T=33
        const int nsub = min(S_FUSE, nsteps - s0);
        const float* src = (s0 == 0) ? c0 : out + (size_t)s0 * N;
        hipLaunchKernelGGL(rk4_steps_kernel, dim3(grid), dim3(TPB), 0, stream,
                           src, out, wsf, N, s0, nsub);
    }
}